// Round 6
// baseline (609.843 us; speedup 1.0000x reference)
//
#include <hip/hip_runtime.h>
#include <stdint.h>
#include <string.h>

// B=4,H=16,L=1024,D=64. q,k: fp32 [B,H,L,D]; mask: byte or int32 bool
// (per-block runtime detection); out: fp32 [B,H,L,L].
// out[bh,i,j] = mask ? 0 : sum_d exp(-(qs-ks)^2)/64, rank-paired via stable
// per-(bh,d) argsort of q and k columns.
//
// Ledger: R5 = 507.0us. fills+gaps ~= 362-370 fixed; tr+p1 = 31 (DPP sort
// proven); p2 ~= 105-110 vs floor 53 (byte mask) / 84 (int32 mask).
// THIS ROUND: PROBE. phase2 body looped x2 IN-KERNEL (idempotent; per-thread
// acc zero/read addresses coincide -> existing syncthreads make rep loop
// race-free). Single dispatch ~2xp2 > 161us -> enters top-5 WITH counters:
//   dur/2 = exact p2; FETCH ~160MB => byte mask / ~544MB => int32;
//   VALUBusy/Occupancy/LDS_BANK_CONFLICT identify the limiter.
// transpose + DPP phase1 + launch structure: byte-identical to R5.

#define LL 1024
#define DD 64
#define NBH 64
#define MAT_WORDS ((size_t)NBH * DD * LL)          // 4 Mi words = 16 MiB
#define WS_BYTES (3 * MAT_WORDS * 4)               // pairs + qt + kt = 48 MiB

typedef float    vf4   __attribute__((ext_vector_type(4)));
typedef uint32_t vu4   __attribute__((ext_vector_type(4)));
typedef int32_t  vi4   __attribute__((ext_vector_type(4)));

__device__ __forceinline__ uint32_t f2ord(float x) {
    uint32_t u = __float_as_uint(x);
    return (u & 0x80000000u) ? ~u : (u | 0x80000000u);
}
__device__ __forceinline__ float ord2f(uint32_t o) {
    uint32_t u = (o & 0x80000000u) ? (o & 0x7fffffffu) : ~o;
    return __uint_as_float(u);
}

// ---- cross-lane fetch primitives (u64 as 2 dwords) ----
template <int CTRL>
__device__ __forceinline__ uint64_t dpp64(uint64_t v) {
    const uint32_t lo = (uint32_t)__builtin_amdgcn_update_dpp(
        0, (int)(uint32_t)v, CTRL, 0xF, 0xF, true);
    const uint32_t hi = (uint32_t)__builtin_amdgcn_update_dpp(
        0, (int)(uint32_t)(v >> 32), CTRL, 0xF, 0xF, true);
    return ((uint64_t)hi << 32) | lo;
}
template <int PATT>
__device__ __forceinline__ uint64_t swz64(uint64_t v) {
    const uint32_t lo = (uint32_t)__builtin_amdgcn_ds_swizzle(
        (int)(uint32_t)v, PATT);
    const uint32_t hi = (uint32_t)__builtin_amdgcn_ds_swizzle(
        (int)(uint32_t)(v >> 32), PATT);
    return ((uint64_t)hi << 32) | lo;
}
__device__ __forceinline__ uint64_t bper64(uint64_t v, int addr) {
    const uint32_t lo = (uint32_t)__builtin_amdgcn_ds_bpermute(
        addr, (int)(uint32_t)v);
    const uint32_t hi = (uint32_t)__builtin_amdgcn_ds_bpermute(
        addr, (int)(uint32_t)(v >> 32));
    return ((uint64_t)hi << 32) | lo;
}
// lane-xor fetchers: x1,x2 direct quad_perm; x4=^7∘^3, x8=^15∘^7 composed;
// x3,x7,x15 are lane-mirrors; x16,x31 ds_swizzle BitMode.
__device__ __forceinline__ uint64_t fx1 (uint64_t v){ return dpp64<0xB1>(v); }
__device__ __forceinline__ uint64_t fx2 (uint64_t v){ return dpp64<0x4E>(v); }
__device__ __forceinline__ uint64_t fx3 (uint64_t v){ return dpp64<0x1B>(v); }
__device__ __forceinline__ uint64_t fx4 (uint64_t v){ return dpp64<0x1B>(dpp64<0x141>(v)); }
__device__ __forceinline__ uint64_t fx7 (uint64_t v){ return dpp64<0x141>(v); }
__device__ __forceinline__ uint64_t fx8 (uint64_t v){ return dpp64<0x141>(dpp64<0x140>(v)); }
__device__ __forceinline__ uint64_t fx15(uint64_t v){ return dpp64<0x140>(v); }
__device__ __forceinline__ uint64_t fx16(uint64_t v){ return swz64<0x401F>(v); }
__device__ __forceinline__ uint64_t fx31(uint64_t v){ return swz64<0x7C1F>(v); }

// full ascending sort of 1024 u64 keys, element p = 16*lane + s.
// Mirror-first bitonic: every merge S starts with mirror CE (p <-> S-1-p),
// then xor steps S/4..1, ALL directions ascending (no up/down logic).
__device__ __forceinline__ void wave_sort1024(uint64_t x[16], const int lane,
                                              const int addr63)
{
    auto cexA = [](uint64_t& a, uint64_t& b) {
        const uint64_t lo = a < b ? a : b;
        const uint64_t hi = a < b ? b : a;
        a = lo; b = hi;
    };
    auto sel = [](uint64_t xv, uint64_t y, bool km) {
        return ((xv < y) == km) ? xv : y;      // km: keep min, else keep max
    };

#define TAIL4() do { _Pragma("unroll") \
    for (int j = 8; j >= 1; j >>= 1) { _Pragma("unroll") \
        for (int s = 0; s < 16; ++s) \
            if (!(s & j)) cexA(x[s], x[s | j]); } } while (0)

#define MIRROR(F, KM) do { _Pragma("unroll") \
    for (int i = 0; i < 8; ++i) { \
        const uint64_t ya = F(x[15 - i]); \
        const uint64_t yb = F(x[i]); \
        x[i]      = sel(x[i],      ya, (KM)); \
        x[15 - i] = sel(x[15 - i], yb, (KM)); } } while (0)

#define XORST(F, KM) do { _Pragma("unroll") \
    for (int s = 0; s < 16; ++s) { \
        const uint64_t y = F(x[s]); \
        x[s] = sel(x[s], y, (KM)); } } while (0)

    // ---- in-register prelude: S = 2,4,8,16 (per-lane 16-elem sort) ----
    #pragma unroll
    for (int s = 0; s < 16; s += 2) cexA(x[s], x[s + 1]);          // S=2
    #pragma unroll
    for (int b = 0; b < 16; b += 4) {                              // S=4 M
        cexA(x[b], x[b + 3]); cexA(x[b + 1], x[b + 2]);
    }
    #pragma unroll
    for (int s = 0; s < 16; s += 2) cexA(x[s], x[s + 1]);          // S=4 j1
    #pragma unroll
    for (int b = 0; b < 16; b += 8) {                              // S=8 M
        cexA(x[b], x[b + 7]); cexA(x[b + 1], x[b + 6]);
        cexA(x[b + 2], x[b + 5]); cexA(x[b + 3], x[b + 4]);
    }
    #pragma unroll
    for (int j = 2; j >= 1; j >>= 1) {                             // S=8 tail
        #pragma unroll
        for (int s = 0; s < 16; ++s)
            if (!(s & j)) cexA(x[s], x[s | j]);
    }
    #pragma unroll
    for (int i = 0; i < 8; ++i) cexA(x[i], x[15 - i]);             // S=16 M
    #pragma unroll
    for (int j = 4; j >= 1; j >>= 1) {                             // S=16 tail
        #pragma unroll
        for (int s = 0; s < 16; ++s)
            if (!(s & j)) cexA(x[s], x[s | j]);
    }

    // ---- cross-lane merges ----
    { const bool km = (lane & 1) == 0;                 // S=32
      MIRROR(fx1, km); TAIL4(); }
    { const bool kmM = (lane & 2) == 0;                // S=64
      MIRROR(fx3, kmM);
      const bool k1 = (lane & 1) == 0; XORST(fx1, k1); TAIL4(); }
    { const bool kmM = (lane & 4) == 0;                // S=128
      MIRROR(fx7, kmM);
      const bool k2 = (lane & 2) == 0; XORST(fx2, k2);
      const bool k1 = (lane & 1) == 0; XORST(fx1, k1); TAIL4(); }
    { const bool kmM = (lane & 8) == 0;                // S=256
      MIRROR(fx15, kmM);
      const bool k4 = (lane & 4) == 0; XORST(fx4, k4);
      const bool k2 = (lane & 2) == 0; XORST(fx2, k2);
      const bool k1 = (lane & 1) == 0; XORST(fx1, k1); TAIL4(); }
    { const bool kmM = (lane & 16) == 0;               // S=512
      MIRROR(fx31, kmM);
      const bool k8 = (lane & 8) == 0; XORST(fx8, k8);
      const bool k4 = (lane & 4) == 0; XORST(fx4, k4);
      const bool k2 = (lane & 2) == 0; XORST(fx2, k2);
      const bool k1 = (lane & 1) == 0; XORST(fx1, k1); TAIL4(); }
    { const bool kmM = (lane & 32) == 0;               // S=1024
      #pragma unroll
      for (int i = 0; i < 8; ++i) {                    // mirror ^63: bpermute
          const uint64_t ya = bper64(x[15 - i], addr63);
          const uint64_t yb = bper64(x[i], addr63);
          x[i]      = sel(x[i],      ya, kmM);
          x[15 - i] = sel(x[15 - i], yb, kmM);
      }
      const bool k16 = (lane & 16) == 0; XORST(fx16, k16);
      const bool k8  = (lane & 8)  == 0; XORST(fx8,  k8);
      const bool k4  = (lane & 4)  == 0; XORST(fx4,  k4);
      const bool k2  = (lane & 2)  == 0; XORST(fx2,  k2);
      const bool k1  = (lane & 1)  == 0; XORST(fx1,  k1); TAIL4(); }

#undef TAIL4
#undef MIRROR
#undef XORST
}

// ---------- kernel 0: tile-transpose q,k -> qt,kt[bh][d][e] as f2ord u32 ---
__global__ __launch_bounds__(256) void swd3_transpose(
    const float* __restrict__ q, const float* __restrict__ k,
    uint32_t* __restrict__ qt, uint32_t* __restrict__ kt)
{
    __shared__ uint32_t tq[64][65];                 // +1 pad: col reads
    __shared__ uint32_t tk[64][65];                 //   conflict-free

    const int b  = blockIdx.x;                      // 0..1023
    const int bh = (b & 7) * 8 + ((b >> 3) & 7);    // XCD b%8 <-> bh>>3
    const int e0 = (b >> 6) * 64;                   // e-tile 0..15
    const int t  = threadIdx.x;

    const size_t base = (size_t)bh * (LL * DD);
    #pragma unroll
    for (int i = 0; i < 4; ++i) {
        const int idx = i * 256 + t;                // 0..1023
        const int r   = idx >> 4;                   // row in tile 0..63
        const int c   = (idx & 15) * 4;             // col 0,4,..,60
        const vf4 vq = *(const vf4*)(q + base + (size_t)(e0 + r) * DD + c);
        const vf4 vk = *(const vf4*)(k + base + (size_t)(e0 + r) * DD + c);
        tq[r][c + 0] = f2ord(vq.x); tq[r][c + 1] = f2ord(vq.y);
        tq[r][c + 2] = f2ord(vq.z); tq[r][c + 3] = f2ord(vq.w);
        tk[r][c + 0] = f2ord(vk.x); tk[r][c + 1] = f2ord(vk.y);
        tk[r][c + 2] = f2ord(vk.z); tk[r][c + 3] = f2ord(vk.w);
    }
    __syncthreads();
    #pragma unroll
    for (int i = 0; i < 4; ++i) {
        const int idx = i * 256 + t;
        const int d   = idx >> 4;                   // out row (dim) 0..63
        const int c   = (idx & 15) * 4;             // e-offset in tile
        vu4 v;
        v.x = tq[c + 0][d]; v.y = tq[c + 1][d];
        v.z = tq[c + 2][d]; v.w = tq[c + 3][d];
        *(vu4*)(qt + base + (size_t)d * LL + e0 + c) = v;
        v.x = tk[c + 0][d]; v.y = tk[c + 1][d];
        v.z = tk[c + 2][d]; v.w = tk[c + 3][d];
        *(vu4*)(kt + base + (size_t)d * LL + e0 + c) = v;
    }
}

// ---------- phase 1: coalesced loads + mirror/DPP bitonic argsort ----------
__global__ __launch_bounds__(256, 3) void swd3_phase1(
    const uint32_t* __restrict__ qt, const uint32_t* __restrict__ kt,
    uint32_t* __restrict__ pairs)
{
    __shared__ alignas(16) uint32_t pr[4][LL];      // 4 KiB per wave, private

    const int raw  = blockIdx.x;                    // 0..1023
    const int slot = raw >> 3;                      // 0..127
    const int bh   = (raw & 7) * 8 + (slot >> 4);   // XCD raw%8 <-> bh>>3
    const int dg   = slot & 15;
    const int t    = threadIdx.x;
    const int w    = t >> 6;                        // wave 0..3
    const int lane = t & 63;
    const int d    = dg * 4 + w;
    const int addr63 = (lane ^ 63) << 2;            // bpermute byte addr

    const uint32_t* colq = qt + (size_t)bh * (DD * LL) + (size_t)d * LL;
    const uint32_t* colk = kt + (size_t)bh * (DD * LL) + (size_t)d * LL;

    uint64_t xq[16], xk[16];
    #pragma unroll
    for (int r = 0; r < 4; ++r) {
        const vu4 vq = *(const vu4*)(colq + 256 * r + 4 * lane);
        const vu4 vk = *(const vu4*)(colk + 256 * r + 4 * lane);
        const uint32_t eb = 256u * r + 4u * lane;
        xq[4 * r + 0] = ((uint64_t)vq.x << 32) | (eb + 0);
        xq[4 * r + 1] = ((uint64_t)vq.y << 32) | (eb + 1);
        xq[4 * r + 2] = ((uint64_t)vq.z << 32) | (eb + 2);
        xq[4 * r + 3] = ((uint64_t)vq.w << 32) | (eb + 3);
        xk[4 * r + 0] = ((uint64_t)vk.x << 32) | (eb + 0);
        xk[4 * r + 1] = ((uint64_t)vk.y << 32) | (eb + 1);
        xk[4 * r + 2] = ((uint64_t)vk.z << 32) | (eb + 2);
        xk[4 * r + 3] = ((uint64_t)vk.w << 32) | (eb + 3);
    }
    wave_sort1024(xq, lane, addr63);
    wave_sort1024(xk, lane, addr63);

    // rank r pairs q-rank-r with k-rank-r; scatter packed
    // {val fp32 top22, low10 = k-index} by q-index into wave-private LDS.
    uint32_t* prw = pr[w];
    #pragma unroll
    for (int s = 0; s < 16; ++s) {
        const uint32_t iq = (uint32_t)xq[s] & 1023u;
        const uint32_t ik = (uint32_t)xk[s] & 1023u;
        const float df = ord2f((uint32_t)(xq[s] >> 32))
                       - ord2f((uint32_t)(xk[s] >> 32));
        const float val = __expf(-df * df) * (1.0f / 64.0f);
        prw[iq] = (__float_as_uint(val) & 0xFFFFFC00u) | ik;   // rel err<2^-12
    }
    __asm__ volatile("s_waitcnt lgkmcnt(0)" ::: "memory");  // wave-local drain
    vu4* pp4 = (vu4*)(pairs + ((size_t)bh * DD + d) * LL);
    const vu4* src = (const vu4*)prw;
    #pragma unroll
    for (int r = 0; r < 4; ++r)
        pp4[r * 64 + lane] = src[r * 64 + lane];
}

// ---------- phase 2: PROBE — body looped x2 in-kernel (idempotent) ---------
__global__ __launch_bounds__(256) void swd3_phase2(
    const uint32_t* __restrict__ pairs, const void* __restrict__ maskp,
    float* __restrict__ out)
{
    __shared__ alignas(16) float acc[8 * LL];       // 32 KiB
    __shared__ uint32_t sdet[4];

    const int b  = blockIdx.x;                      // 0..8191
    const int bh = (b & 7) * 8 + ((b >> 3) & 7);    // XCD b%8 <-> bh>>3
    const int st = b >> 6;                          // stripe 0..127
    const int i0 = st * 8;
    const int t  = threadIdx.x;

    // inline mask-width detect on the globally-shared first 1 KiB of mask
    {
        const uint32_t w = ((const uint32_t*)maskp)[t];
        const uint64_t bal = __ballot(w > 1u);
        if ((t & 63) == 0) sdet[t >> 6] = (bal != 0ull) ? 1u : 0u;
    }

    vf4* acc4 = (vf4*)acc;
    const size_t cellbase = ((size_t)bh << 20) + ((size_t)i0 << 10);

    #pragma unroll 1
    for (int rep = 0; rep < 2; ++rep) {
        // zero: thread t touches exactly the words it later reads (no
        // cross-thread hazard vs rep-1 reads; atomics gated by syncthreads)
        #pragma unroll
        for (int v = 0; v < 8; ++v) {
            vf4 z; z.x = 0.f; z.y = 0.f; z.z = 0.f; z.w = 0.f;
            acc4[v * 256 + t] = z;
        }
        __syncthreads();

        const bool mask_byte =
            ((sdet[0] | sdet[1] | sdet[2] | sdet[3]) != 0u);

        // prefetch mask into registers (NT); loads fly during the scatter
        uint32_t mb[8];
        vi4      mi[8];
        if (mask_byte) {
            const uint32_t* mp = (const uint32_t*)maskp + (cellbase >> 2);
            #pragma unroll
            for (int v = 0; v < 8; ++v)
                mb[v] = __builtin_nontemporal_load(mp + v * 256 + t);
        } else {
            const vi4* mp = (const vi4*)((const int32_t*)maskp + cellbase);
            #pragma unroll
            for (int v = 0; v < 8; ++v)
                mi[v] = __builtin_nontemporal_load(mp + v * 256 + t);
        }

        // 512 records as 256 uint2: t -> dd=t>>2, rows 2*(t&3), 2*(t&3)+1
        {
            const uint32_t* pb = pairs + (size_t)bh * (DD * LL);
            const int dd = t >> 2;
            const uint2 pv = ((const uint2*)(pb + dd * LL + i0))[t & 3];
            const int ii0 = 2 * (t & 3), ii1 = ii0 + 1;
            atomicAdd(&acc[ii0 * LL + (int)(pv.x & 1023u)],
                      __uint_as_float(pv.x & 0xFFFFFC00u));
            atomicAdd(&acc[ii1 * LL + (int)(pv.y & 1023u)],
                      __uint_as_float(pv.y & 0xFFFFFC00u));
        }
        __syncthreads();

        vf4* ob = (vf4*)(out + cellbase);
        #pragma unroll
        for (int v = 0; v < 8; ++v) {
            const int p = v * 256 + t;              // vf4 group in [0,2048)
            const vf4 a = acc4[p];
            int mx, my, mz, mw2;
            if (mask_byte) {
                const uint32_t m = mb[v];
                mx = (int)(m & 0xFFu); my = (int)((m >> 8) & 0xFFu);
                mz = (int)((m >> 16) & 0xFFu); mw2 = (int)(m >> 24);
            } else {
                mx = mi[v].x; my = mi[v].y; mz = mi[v].z; mw2 = mi[v].w;
            }
            vf4 r;
            r.x = mx  ? 0.f : a.x;
            r.y = my  ? 0.f : a.y;
            r.z = mz  ? 0.f : a.z;
            r.w = mw2 ? 0.f : a.w;
            __builtin_nontemporal_store(r, ob + p);
        }
    }
}

extern "C" void kernel_launch(void* const* d_in, const int* in_sizes, int n_in,
                              void* d_out, int out_size, void* d_ws, size_t ws_size,
                              hipStream_t stream) {
    const float* q = (const float*)d_in[0];
    const float* k = (const float*)d_in[1];
    const void* mask = d_in[2];
    uint32_t* pairs = (uint32_t*)d_ws;
    uint32_t* qt = pairs + MAT_WORDS;
    uint32_t* kt = qt + MAT_WORDS;

    const bool ws_ok = (ws_size >= WS_BYTES);
    hipError_t e0 = hipSuccess, e1 = hipSuccess, e2 = hipSuccess;
    (void)hipGetLastError();

    if (ws_ok) {
        swd3_transpose<<<NBH * 16, 256, 0, stream>>>(q, k, qt, kt);
        e0 = hipGetLastError();
        swd3_phase1<<<NBH * DD / 4, 256, 0, stream>>>(qt, kt, pairs);
        e1 = hipGetLastError();
        swd3_phase2<<<NBH * 128, 256, 0, stream>>>(pairs, mask, (float*)d_out);
        e2 = hipGetLastError();
    }

    if (!ws_ok || e0 != hipSuccess || e1 != hipSuccess || e2 != hipSuccess) {
        // Diagnostic stamp (fp32 codes): absmax reveals which enqueue failed.
        static float h_stamp[8];
        h_stamp[0] = !ws_ok ? (9000.0f + (float)(ws_size >> 20))
                            : (1000.0f + (float)(int)e0);
        h_stamp[1] = 2000.0f + (float)(int)e1;
        h_stamp[2] = 3000.0f + (float)(int)e2;
        h_stamp[3] = h_stamp[0];
        hipMemcpyAsync(d_out, h_stamp, sizeof(h_stamp),
                       hipMemcpyHostToDevice, stream);
    }
}

// Round 7
// 526.677 us; speedup vs baseline: 1.1579x; 1.1579x over previous
//
#include <hip/hip_runtime.h>
#include <stdint.h>
#include <string.h>

// B=4,H=16,L=1024,D=64. q,k: fp32 [B,H,L,D]; mask: byte or int32 bool
// (runtime detection; R6 FETCH evidence => int32 on this harness);
// out: fp32 [B,H,L,L].
// out[bh,i,j] = mask ? 0 : sum_d exp(-(qs-ks)^2)/64, rank-paired via stable
// per-(bh,d) argsort of q and k columns.
//
// Ledger: R5=507us. fills+gaps ~370 fixed; tr+p1=31 (DPP mirror sort,
// proven R5); p2=101 (measured R6 via x2-rep probe: occupancy 36%, hbm 50%,
// VALU 8.5% -> latency/occupancy-bound; mask=int32, ~55% L3-absorbed).
// THIS ROUND: phase2 rewritten wave-autonomous: 1 wave = 1 row (4 rows/wave
// via uint4 record gather from L3-resident pairs). Per row: zero 4KiB LDS
// row -> 1 ds_add_f32/lane -> readback+mask+NT store. 16KiB LDS/block,
// ZERO __syncthreads (wave-local lgkmcnt drains), wave-ballot mask detect,
// __launch_bounds__(256,8) -> target 8 blocks/CU (100% occupancy vs 36%).
// transpose + phase1: byte-identical to R5. x2-rep probe reverted.

#define LL 1024
#define DD 64
#define NBH 64
#define MAT_WORDS ((size_t)NBH * DD * LL)          // 4 Mi words = 16 MiB
#define WS_BYTES (3 * MAT_WORDS * 4)               // pairs + qt + kt = 48 MiB

typedef float    vf4   __attribute__((ext_vector_type(4)));
typedef uint32_t vu4   __attribute__((ext_vector_type(4)));
typedef int32_t  vi4   __attribute__((ext_vector_type(4)));

__device__ __forceinline__ uint32_t f2ord(float x) {
    uint32_t u = __float_as_uint(x);
    return (u & 0x80000000u) ? ~u : (u | 0x80000000u);
}
__device__ __forceinline__ float ord2f(uint32_t o) {
    uint32_t u = (o & 0x80000000u) ? (o & 0x7fffffffu) : ~o;
    return __uint_as_float(u);
}

// ---- cross-lane fetch primitives (u64 as 2 dwords) ----
template <int CTRL>
__device__ __forceinline__ uint64_t dpp64(uint64_t v) {
    const uint32_t lo = (uint32_t)__builtin_amdgcn_update_dpp(
        0, (int)(uint32_t)v, CTRL, 0xF, 0xF, true);
    const uint32_t hi = (uint32_t)__builtin_amdgcn_update_dpp(
        0, (int)(uint32_t)(v >> 32), CTRL, 0xF, 0xF, true);
    return ((uint64_t)hi << 32) | lo;
}
template <int PATT>
__device__ __forceinline__ uint64_t swz64(uint64_t v) {
    const uint32_t lo = (uint32_t)__builtin_amdgcn_ds_swizzle(
        (int)(uint32_t)v, PATT);
    const uint32_t hi = (uint32_t)__builtin_amdgcn_ds_swizzle(
        (int)(uint32_t)(v >> 32), PATT);
    return ((uint64_t)hi << 32) | lo;
}
__device__ __forceinline__ uint64_t bper64(uint64_t v, int addr) {
    const uint32_t lo = (uint32_t)__builtin_amdgcn_ds_bpermute(
        addr, (int)(uint32_t)v);
    const uint32_t hi = (uint32_t)__builtin_amdgcn_ds_bpermute(
        addr, (int)(uint32_t)(v >> 32));
    return ((uint64_t)hi << 32) | lo;
}
// lane-xor fetchers: x1,x2 direct quad_perm; x4=^7∘^3, x8=^15∘^7 composed;
// x3,x7,x15 are lane-mirrors; x16,x31 ds_swizzle BitMode.
__device__ __forceinline__ uint64_t fx1 (uint64_t v){ return dpp64<0xB1>(v); }
__device__ __forceinline__ uint64_t fx2 (uint64_t v){ return dpp64<0x4E>(v); }
__device__ __forceinline__ uint64_t fx3 (uint64_t v){ return dpp64<0x1B>(v); }
__device__ __forceinline__ uint64_t fx4 (uint64_t v){ return dpp64<0x1B>(dpp64<0x141>(v)); }
__device__ __forceinline__ uint64_t fx7 (uint64_t v){ return dpp64<0x141>(v); }
__device__ __forceinline__ uint64_t fx8 (uint64_t v){ return dpp64<0x141>(dpp64<0x140>(v)); }
__device__ __forceinline__ uint64_t fx15(uint64_t v){ return dpp64<0x140>(v); }
__device__ __forceinline__ uint64_t fx16(uint64_t v){ return swz64<0x401F>(v); }
__device__ __forceinline__ uint64_t fx31(uint64_t v){ return swz64<0x7C1F>(v); }

// full ascending sort of 1024 u64 keys, element p = 16*lane + s.
// Mirror-first bitonic: every merge S starts with mirror CE (p <-> S-1-p),
// then xor steps S/4..1, ALL directions ascending (no up/down logic).
__device__ __forceinline__ void wave_sort1024(uint64_t x[16], const int lane,
                                              const int addr63)
{
    auto cexA = [](uint64_t& a, uint64_t& b) {
        const uint64_t lo = a < b ? a : b;
        const uint64_t hi = a < b ? b : a;
        a = lo; b = hi;
    };
    auto sel = [](uint64_t xv, uint64_t y, bool km) {
        return ((xv < y) == km) ? xv : y;      // km: keep min, else keep max
    };

#define TAIL4() do { _Pragma("unroll") \
    for (int j = 8; j >= 1; j >>= 1) { _Pragma("unroll") \
        for (int s = 0; s < 16; ++s) \
            if (!(s & j)) cexA(x[s], x[s | j]); } } while (0)

#define MIRROR(F, KM) do { _Pragma("unroll") \
    for (int i = 0; i < 8; ++i) { \
        const uint64_t ya = F(x[15 - i]); \
        const uint64_t yb = F(x[i]); \
        x[i]      = sel(x[i],      ya, (KM)); \
        x[15 - i] = sel(x[15 - i], yb, (KM)); } } while (0)

#define XORST(F, KM) do { _Pragma("unroll") \
    for (int s = 0; s < 16; ++s) { \
        const uint64_t y = F(x[s]); \
        x[s] = sel(x[s], y, (KM)); } } while (0)

    // ---- in-register prelude: S = 2,4,8,16 (per-lane 16-elem sort) ----
    #pragma unroll
    for (int s = 0; s < 16; s += 2) cexA(x[s], x[s + 1]);          // S=2
    #pragma unroll
    for (int b = 0; b < 16; b += 4) {                              // S=4 M
        cexA(x[b], x[b + 3]); cexA(x[b + 1], x[b + 2]);
    }
    #pragma unroll
    for (int s = 0; s < 16; s += 2) cexA(x[s], x[s + 1]);          // S=4 j1
    #pragma unroll
    for (int b = 0; b < 16; b += 8) {                              // S=8 M
        cexA(x[b], x[b + 7]); cexA(x[b + 1], x[b + 6]);
        cexA(x[b + 2], x[b + 5]); cexA(x[b + 3], x[b + 4]);
    }
    #pragma unroll
    for (int j = 2; j >= 1; j >>= 1) {                             // S=8 tail
        #pragma unroll
        for (int s = 0; s < 16; ++s)
            if (!(s & j)) cexA(x[s], x[s | j]);
    }
    #pragma unroll
    for (int i = 0; i < 8; ++i) cexA(x[i], x[15 - i]);             // S=16 M
    #pragma unroll
    for (int j = 4; j >= 1; j >>= 1) {                             // S=16 tail
        #pragma unroll
        for (int s = 0; s < 16; ++s)
            if (!(s & j)) cexA(x[s], x[s | j]);
    }

    // ---- cross-lane merges ----
    { const bool km = (lane & 1) == 0;                 // S=32
      MIRROR(fx1, km); TAIL4(); }
    { const bool kmM = (lane & 2) == 0;                // S=64
      MIRROR(fx3, kmM);
      const bool k1 = (lane & 1) == 0; XORST(fx1, k1); TAIL4(); }
    { const bool kmM = (lane & 4) == 0;                // S=128
      MIRROR(fx7, kmM);
      const bool k2 = (lane & 2) == 0; XORST(fx2, k2);
      const bool k1 = (lane & 1) == 0; XORST(fx1, k1); TAIL4(); }
    { const bool kmM = (lane & 8) == 0;                // S=256
      MIRROR(fx15, kmM);
      const bool k4 = (lane & 4) == 0; XORST(fx4, k4);
      const bool k2 = (lane & 2) == 0; XORST(fx2, k2);
      const bool k1 = (lane & 1) == 0; XORST(fx1, k1); TAIL4(); }
    { const bool kmM = (lane & 16) == 0;               // S=512
      MIRROR(fx31, kmM);
      const bool k8 = (lane & 8) == 0; XORST(fx8, k8);
      const bool k4 = (lane & 4) == 0; XORST(fx4, k4);
      const bool k2 = (lane & 2) == 0; XORST(fx2, k2);
      const bool k1 = (lane & 1) == 0; XORST(fx1, k1); TAIL4(); }
    { const bool kmM = (lane & 32) == 0;               // S=1024
      #pragma unroll
      for (int i = 0; i < 8; ++i) {                    // mirror ^63: bpermute
          const uint64_t ya = bper64(x[15 - i], addr63);
          const uint64_t yb = bper64(x[i], addr63);
          x[i]      = sel(x[i],      ya, kmM);
          x[15 - i] = sel(x[15 - i], yb, kmM);
      }
      const bool k16 = (lane & 16) == 0; XORST(fx16, k16);
      const bool k8  = (lane & 8)  == 0; XORST(fx8,  k8);
      const bool k4  = (lane & 4)  == 0; XORST(fx4,  k4);
      const bool k2  = (lane & 2)  == 0; XORST(fx2,  k2);
      const bool k1  = (lane & 1)  == 0; XORST(fx1,  k1); TAIL4(); }

#undef TAIL4
#undef MIRROR
#undef XORST
}

// ---------- kernel 0: tile-transpose q,k -> qt,kt[bh][d][e] as f2ord u32 ---
__global__ __launch_bounds__(256) void swd3_transpose(
    const float* __restrict__ q, const float* __restrict__ k,
    uint32_t* __restrict__ qt, uint32_t* __restrict__ kt)
{
    __shared__ uint32_t tq[64][65];                 // +1 pad: col reads
    __shared__ uint32_t tk[64][65];                 //   conflict-free

    const int b  = blockIdx.x;                      // 0..1023
    const int bh = (b & 7) * 8 + ((b >> 3) & 7);    // XCD b%8 <-> bh>>3
    const int e0 = (b >> 6) * 64;                   // e-tile 0..15
    const int t  = threadIdx.x;

    const size_t base = (size_t)bh * (LL * DD);
    #pragma unroll
    for (int i = 0; i < 4; ++i) {
        const int idx = i * 256 + t;                // 0..1023
        const int r   = idx >> 4;                   // row in tile 0..63
        const int c   = (idx & 15) * 4;             // col 0,4,..,60
        const vf4 vq = *(const vf4*)(q + base + (size_t)(e0 + r) * DD + c);
        const vf4 vk = *(const vf4*)(k + base + (size_t)(e0 + r) * DD + c);
        tq[r][c + 0] = f2ord(vq.x); tq[r][c + 1] = f2ord(vq.y);
        tq[r][c + 2] = f2ord(vq.z); tq[r][c + 3] = f2ord(vq.w);
        tk[r][c + 0] = f2ord(vk.x); tk[r][c + 1] = f2ord(vk.y);
        tk[r][c + 2] = f2ord(vk.z); tk[r][c + 3] = f2ord(vk.w);
    }
    __syncthreads();
    #pragma unroll
    for (int i = 0; i < 4; ++i) {
        const int idx = i * 256 + t;
        const int d   = idx >> 4;                   // out row (dim) 0..63
        const int c   = (idx & 15) * 4;             // e-offset in tile
        vu4 v;
        v.x = tq[c + 0][d]; v.y = tq[c + 1][d];
        v.z = tq[c + 2][d]; v.w = tq[c + 3][d];
        *(vu4*)(qt + base + (size_t)d * LL + e0 + c) = v;
        v.x = tk[c + 0][d]; v.y = tk[c + 1][d];
        v.z = tk[c + 2][d]; v.w = tk[c + 3][d];
        *(vu4*)(kt + base + (size_t)d * LL + e0 + c) = v;
    }
}

// ---------- phase 1: coalesced loads + mirror/DPP bitonic argsort ----------
__global__ __launch_bounds__(256, 3) void swd3_phase1(
    const uint32_t* __restrict__ qt, const uint32_t* __restrict__ kt,
    uint32_t* __restrict__ pairs)
{
    __shared__ alignas(16) uint32_t pr[4][LL];      // 4 KiB per wave, private

    const int raw  = blockIdx.x;                    // 0..1023
    const int slot = raw >> 3;                      // 0..127
    const int bh   = (raw & 7) * 8 + (slot >> 4);   // XCD raw%8 <-> bh>>3
    const int dg   = slot & 15;
    const int t    = threadIdx.x;
    const int w    = t >> 6;                        // wave 0..3
    const int lane = t & 63;
    const int d    = dg * 4 + w;
    const int addr63 = (lane ^ 63) << 2;            // bpermute byte addr

    const uint32_t* colq = qt + (size_t)bh * (DD * LL) + (size_t)d * LL;
    const uint32_t* colk = kt + (size_t)bh * (DD * LL) + (size_t)d * LL;

    uint64_t xq[16], xk[16];
    #pragma unroll
    for (int r = 0; r < 4; ++r) {
        const vu4 vq = *(const vu4*)(colq + 256 * r + 4 * lane);
        const vu4 vk = *(const vu4*)(colk + 256 * r + 4 * lane);
        const uint32_t eb = 256u * r + 4u * lane;
        xq[4 * r + 0] = ((uint64_t)vq.x << 32) | (eb + 0);
        xq[4 * r + 1] = ((uint64_t)vq.y << 32) | (eb + 1);
        xq[4 * r + 2] = ((uint64_t)vq.z << 32) | (eb + 2);
        xq[4 * r + 3] = ((uint64_t)vq.w << 32) | (eb + 3);
        xk[4 * r + 0] = ((uint64_t)vk.x << 32) | (eb + 0);
        xk[4 * r + 1] = ((uint64_t)vk.y << 32) | (eb + 1);
        xk[4 * r + 2] = ((uint64_t)vk.z << 32) | (eb + 2);
        xk[4 * r + 3] = ((uint64_t)vk.w << 32) | (eb + 3);
    }
    wave_sort1024(xq, lane, addr63);
    wave_sort1024(xk, lane, addr63);

    // rank r pairs q-rank-r with k-rank-r; scatter packed
    // {val fp32 top22, low10 = k-index} by q-index into wave-private LDS.
    uint32_t* prw = pr[w];
    #pragma unroll
    for (int s = 0; s < 16; ++s) {
        const uint32_t iq = (uint32_t)xq[s] & 1023u;
        const uint32_t ik = (uint32_t)xk[s] & 1023u;
        const float df = ord2f((uint32_t)(xq[s] >> 32))
                       - ord2f((uint32_t)(xk[s] >> 32));
        const float val = __expf(-df * df) * (1.0f / 64.0f);
        prw[iq] = (__float_as_uint(val) & 0xFFFFFC00u) | ik;   // rel err<2^-12
    }
    __asm__ volatile("s_waitcnt lgkmcnt(0)" ::: "memory");  // wave-local drain
    vu4* pp4 = (vu4*)(pairs + ((size_t)bh * DD + d) * LL);
    const vu4* src = (const vu4*)prw;
    #pragma unroll
    for (int r = 0; r < 4; ++r)
        pp4[r * 64 + lane] = src[r * 64 + lane];
}

// ---------- phase 2: wave-autonomous row assembly, barrier-free ------------
// 1 wave = 4 rows (sequential). Per row: zero 4KiB LDS row -> 1 ds_add/lane
// -> readback + mask + NT store. No __syncthreads anywhere.
__global__ __launch_bounds__(256, 8) void swd3_phase2(
    const uint32_t* __restrict__ pairs, const void* __restrict__ maskp,
    float* __restrict__ out)
{
    __shared__ alignas(16) float rowbuf[4][LL];     // 4 KiB per wave, private

    const int b    = blockIdx.x;                    // 0..4095
    const int bh   = (b & 7) * 8 + ((b >> 3) & 7);  // XCD b%8 <-> bh>>3
    const int g    = b >> 6;                        // row-group 0..63
    const int t    = threadIdx.x;
    const int w    = t >> 6;
    const int lane = t & 63;
    const int i0   = g * 16 + w * 4;                // this wave's 4 rows

    // wave-local mask-width detect (first 256B of mask, L2-hot):
    // byte-mask packs 4 bools/word -> some word >1 w.p. 1-(1/8)^64.
    const uint32_t dw = ((const uint32_t*)maskp)[lane];
    const bool mask_byte = (__ballot(dw > 1u) != 0ull);

    // 4 records for this lane's dim d=lane: pairs[bh][lane][i0..i0+3]
    const uint32_t* pb = pairs + (size_t)bh * (DD * LL);
    const vu4 rec = *(const vu4*)(pb + (size_t)lane * LL + i0);

    float* lrow = rowbuf[w];
    vf4*   l4   = (vf4*)lrow;

    #pragma unroll
    for (int r = 0; r < 4; ++r) {                   // compile-time r (rec[r])
        const int i = i0 + r;
        const size_t cellrow = ((size_t)bh << 20) + ((size_t)i << 10);

        // prefetch this row's mask (NT); flies during zero+scatter
        uint32_t mb[4]; vi4 mi[4];
        if (mask_byte) {
            const uint32_t* mp = (const uint32_t*)maskp + (cellrow >> 2);
            #pragma unroll
            for (int it = 0; it < 4; ++it)
                mb[it] = __builtin_nontemporal_load(mp + it * 64 + lane);
        } else {
            const vi4* mp = (const vi4*)((const int32_t*)maskp + cellrow);
            #pragma unroll
            for (int it = 0; it < 4; ++it)
                mi[it] = __builtin_nontemporal_load(mp + it * 64 + lane);
        }

        // zero wave-private row buffer (4 x ds_write_b128)
        #pragma unroll
        for (int it = 0; it < 4; ++it) {
            vf4 z; z.x = 0.f; z.y = 0.f; z.z = 0.f; z.w = 0.f;
            l4[it * 64 + lane] = z;
        }
        __asm__ volatile("s_waitcnt lgkmcnt(0)" ::: "memory");

        // scatter: one record per lane into the row
        const uint32_t pv = rec[r];
        atomicAdd(&lrow[pv & 1023u], __uint_as_float(pv & 0xFFFFFC00u));
        __asm__ volatile("s_waitcnt lgkmcnt(0)" ::: "memory");

        // readback + mask + NT store (1KB/instr, coalesced)
        vf4* ob = (vf4*)(out + cellrow);
        #pragma unroll
        for (int it = 0; it < 4; ++it) {
            const vf4 a = l4[it * 64 + lane];
            int mx, my, mz, mw2;
            if (mask_byte) {
                const uint32_t m = mb[it];
                mx = (int)(m & 0xFFu); my = (int)((m >> 8) & 0xFFu);
                mz = (int)((m >> 16) & 0xFFu); mw2 = (int)(m >> 24);
            } else {
                mx = mi[it].x; my = mi[it].y; mz = mi[it].z; mw2 = mi[it].w;
            }
            vf4 rr;
            rr.x = mx  ? 0.f : a.x;
            rr.y = my  ? 0.f : a.y;
            rr.z = mz  ? 0.f : a.z;
            rr.w = mw2 ? 0.f : a.w;
            __builtin_nontemporal_store(rr, ob + it * 64 + lane);
        }
        // reads drained before next row's zeroing (wave-local)
        __asm__ volatile("s_waitcnt lgkmcnt(0)" ::: "memory");
    }
}

extern "C" void kernel_launch(void* const* d_in, const int* in_sizes, int n_in,
                              void* d_out, int out_size, void* d_ws, size_t ws_size,
                              hipStream_t stream) {
    const float* q = (const float*)d_in[0];
    const float* k = (const float*)d_in[1];
    const void* mask = d_in[2];
    uint32_t* pairs = (uint32_t*)d_ws;
    uint32_t* qt = pairs + MAT_WORDS;
    uint32_t* kt = qt + MAT_WORDS;

    const bool ws_ok = (ws_size >= WS_BYTES);
    hipError_t e0 = hipSuccess, e1 = hipSuccess, e2 = hipSuccess;
    (void)hipGetLastError();

    if (ws_ok) {
        swd3_transpose<<<NBH * 16, 256, 0, stream>>>(q, k, qt, kt);
        e0 = hipGetLastError();
        swd3_phase1<<<NBH * DD / 4, 256, 0, stream>>>(qt, kt, pairs);
        e1 = hipGetLastError();
        swd3_phase2<<<NBH * 64, 256, 0, stream>>>(pairs, mask, (float*)d_out);
        e2 = hipGetLastError();
    }

    if (!ws_ok || e0 != hipSuccess || e1 != hipSuccess || e2 != hipSuccess) {
        // Diagnostic stamp (fp32 codes): absmax reveals which enqueue failed.
        static float h_stamp[8];
        h_stamp[0] = !ws_ok ? (9000.0f + (float)(ws_size >> 20))
                            : (1000.0f + (float)(int)e0);
        h_stamp[1] = 2000.0f + (float)(int)e1;
        h_stamp[2] = 3000.0f + (float)(int)e2;
        h_stamp[3] = h_stamp[0];
        hipMemcpyAsync(d_out, h_stamp, sizeof(h_stamp),
                       hipMemcpyHostToDevice, stream);
    }
}

// Round 8
// 511.343 us; speedup vs baseline: 1.1926x; 1.0300x over previous
//
#include <hip/hip_runtime.h>
#include <stdint.h>
#include <string.h>

// B=4,H=16,L=1024,D=64. q,k: fp32 [B,H,L,D]; mask: byte or int32 bool
// (runtime detection; R6 FETCH evidence => int32 here, ~50% L3-absorbed);
// out: fp32 [B,H,L,L].
// out[bh,i,j] = mask ? 0 : sum_d exp(-(qs-ks)^2)/64, rank-paired via stable
// per-(bh,d) argsort of q and k columns.
//
// Ledger: R5=507us = fixed fills/gaps ~375 + tr+p1 31 (DPP mirror sort,
// proven) + p2 101 (R6 probe: occ 36%, hbm 50%, VALU 8.5%; traffic floor
// ~83us). R7 wave-autonomous p2 REGRESSED (121us: stride-4KB pairs gather +
// serialized per-row chains). THIS ROUND: p2 reverted to R5 block structure
// at 4 rows/block (LDS 32.5->16.1KiB, 4->8 blocks/CU cap, grid 16384,
// 1 record/thread) — isolated occupancy test on the PROVEN access pattern.
// transpose + phase1: byte-identical to R5.

#define LL 1024
#define DD 64
#define NBH 64
#define MAT_WORDS ((size_t)NBH * DD * LL)          // 4 Mi words = 16 MiB
#define WS_BYTES (3 * MAT_WORDS * 4)               // pairs + qt + kt = 48 MiB

typedef float    vf4   __attribute__((ext_vector_type(4)));
typedef uint32_t vu4   __attribute__((ext_vector_type(4)));
typedef int32_t  vi4   __attribute__((ext_vector_type(4)));

__device__ __forceinline__ uint32_t f2ord(float x) {
    uint32_t u = __float_as_uint(x);
    return (u & 0x80000000u) ? ~u : (u | 0x80000000u);
}
__device__ __forceinline__ float ord2f(uint32_t o) {
    uint32_t u = (o & 0x80000000u) ? (o & 0x7fffffffu) : ~o;
    return __uint_as_float(u);
}

// ---- cross-lane fetch primitives (u64 as 2 dwords) ----
template <int CTRL>
__device__ __forceinline__ uint64_t dpp64(uint64_t v) {
    const uint32_t lo = (uint32_t)__builtin_amdgcn_update_dpp(
        0, (int)(uint32_t)v, CTRL, 0xF, 0xF, true);
    const uint32_t hi = (uint32_t)__builtin_amdgcn_update_dpp(
        0, (int)(uint32_t)(v >> 32), CTRL, 0xF, 0xF, true);
    return ((uint64_t)hi << 32) | lo;
}
template <int PATT>
__device__ __forceinline__ uint64_t swz64(uint64_t v) {
    const uint32_t lo = (uint32_t)__builtin_amdgcn_ds_swizzle(
        (int)(uint32_t)v, PATT);
    const uint32_t hi = (uint32_t)__builtin_amdgcn_ds_swizzle(
        (int)(uint32_t)(v >> 32), PATT);
    return ((uint64_t)hi << 32) | lo;
}
__device__ __forceinline__ uint64_t bper64(uint64_t v, int addr) {
    const uint32_t lo = (uint32_t)__builtin_amdgcn_ds_bpermute(
        addr, (int)(uint32_t)v);
    const uint32_t hi = (uint32_t)__builtin_amdgcn_ds_bpermute(
        addr, (int)(uint32_t)(v >> 32));
    return ((uint64_t)hi << 32) | lo;
}
// lane-xor fetchers: x1,x2 direct quad_perm; x4=^7∘^3, x8=^15∘^7 composed;
// x3,x7,x15 are lane-mirrors; x16,x31 ds_swizzle BitMode.
__device__ __forceinline__ uint64_t fx1 (uint64_t v){ return dpp64<0xB1>(v); }
__device__ __forceinline__ uint64_t fx2 (uint64_t v){ return dpp64<0x4E>(v); }
__device__ __forceinline__ uint64_t fx3 (uint64_t v){ return dpp64<0x1B>(v); }
__device__ __forceinline__ uint64_t fx4 (uint64_t v){ return dpp64<0x1B>(dpp64<0x141>(v)); }
__device__ __forceinline__ uint64_t fx7 (uint64_t v){ return dpp64<0x141>(v); }
__device__ __forceinline__ uint64_t fx8 (uint64_t v){ return dpp64<0x141>(dpp64<0x140>(v)); }
__device__ __forceinline__ uint64_t fx15(uint64_t v){ return dpp64<0x140>(v); }
__device__ __forceinline__ uint64_t fx16(uint64_t v){ return swz64<0x401F>(v); }
__device__ __forceinline__ uint64_t fx31(uint64_t v){ return swz64<0x7C1F>(v); }

// full ascending sort of 1024 u64 keys, element p = 16*lane + s.
// Mirror-first bitonic: every merge S starts with mirror CE (p <-> S-1-p),
// then xor steps S/4..1, ALL directions ascending (no up/down logic).
__device__ __forceinline__ void wave_sort1024(uint64_t x[16], const int lane,
                                              const int addr63)
{
    auto cexA = [](uint64_t& a, uint64_t& b) {
        const uint64_t lo = a < b ? a : b;
        const uint64_t hi = a < b ? b : a;
        a = lo; b = hi;
    };
    auto sel = [](uint64_t xv, uint64_t y, bool km) {
        return ((xv < y) == km) ? xv : y;      // km: keep min, else keep max
    };

#define TAIL4() do { _Pragma("unroll") \
    for (int j = 8; j >= 1; j >>= 1) { _Pragma("unroll") \
        for (int s = 0; s < 16; ++s) \
            if (!(s & j)) cexA(x[s], x[s | j]); } } while (0)

#define MIRROR(F, KM) do { _Pragma("unroll") \
    for (int i = 0; i < 8; ++i) { \
        const uint64_t ya = F(x[15 - i]); \
        const uint64_t yb = F(x[i]); \
        x[i]      = sel(x[i],      ya, (KM)); \
        x[15 - i] = sel(x[15 - i], yb, (KM)); } } while (0)

#define XORST(F, KM) do { _Pragma("unroll") \
    for (int s = 0; s < 16; ++s) { \
        const uint64_t y = F(x[s]); \
        x[s] = sel(x[s], y, (KM)); } } while (0)

    // ---- in-register prelude: S = 2,4,8,16 (per-lane 16-elem sort) ----
    #pragma unroll
    for (int s = 0; s < 16; s += 2) cexA(x[s], x[s + 1]);          // S=2
    #pragma unroll
    for (int b = 0; b < 16; b += 4) {                              // S=4 M
        cexA(x[b], x[b + 3]); cexA(x[b + 1], x[b + 2]);
    }
    #pragma unroll
    for (int s = 0; s < 16; s += 2) cexA(x[s], x[s + 1]);          // S=4 j1
    #pragma unroll
    for (int b = 0; b < 16; b += 8) {                              // S=8 M
        cexA(x[b], x[b + 7]); cexA(x[b + 1], x[b + 6]);
        cexA(x[b + 2], x[b + 5]); cexA(x[b + 3], x[b + 4]);
    }
    #pragma unroll
    for (int j = 2; j >= 1; j >>= 1) {                             // S=8 tail
        #pragma unroll
        for (int s = 0; s < 16; ++s)
            if (!(s & j)) cexA(x[s], x[s | j]);
    }
    #pragma unroll
    for (int i = 0; i < 8; ++i) cexA(x[i], x[15 - i]);             // S=16 M
    #pragma unroll
    for (int j = 4; j >= 1; j >>= 1) {                             // S=16 tail
        #pragma unroll
        for (int s = 0; s < 16; ++s)
            if (!(s & j)) cexA(x[s], x[s | j]);
    }

    // ---- cross-lane merges ----
    { const bool km = (lane & 1) == 0;                 // S=32
      MIRROR(fx1, km); TAIL4(); }
    { const bool kmM = (lane & 2) == 0;                // S=64
      MIRROR(fx3, kmM);
      const bool k1 = (lane & 1) == 0; XORST(fx1, k1); TAIL4(); }
    { const bool kmM = (lane & 4) == 0;                // S=128
      MIRROR(fx7, kmM);
      const bool k2 = (lane & 2) == 0; XORST(fx2, k2);
      const bool k1 = (lane & 1) == 0; XORST(fx1, k1); TAIL4(); }
    { const bool kmM = (lane & 8) == 0;                // S=256
      MIRROR(fx15, kmM);
      const bool k4 = (lane & 4) == 0; XORST(fx4, k4);
      const bool k2 = (lane & 2) == 0; XORST(fx2, k2);
      const bool k1 = (lane & 1) == 0; XORST(fx1, k1); TAIL4(); }
    { const bool kmM = (lane & 16) == 0;               // S=512
      MIRROR(fx31, kmM);
      const bool k8 = (lane & 8) == 0; XORST(fx8, k8);
      const bool k4 = (lane & 4) == 0; XORST(fx4, k4);
      const bool k2 = (lane & 2) == 0; XORST(fx2, k2);
      const bool k1 = (lane & 1) == 0; XORST(fx1, k1); TAIL4(); }
    { const bool kmM = (lane & 32) == 0;               // S=1024
      #pragma unroll
      for (int i = 0; i < 8; ++i) {                    // mirror ^63: bpermute
          const uint64_t ya = bper64(x[15 - i], addr63);
          const uint64_t yb = bper64(x[i], addr63);
          x[i]      = sel(x[i],      ya, kmM);
          x[15 - i] = sel(x[15 - i], yb, kmM);
      }
      const bool k16 = (lane & 16) == 0; XORST(fx16, k16);
      const bool k8  = (lane & 8)  == 0; XORST(fx8,  k8);
      const bool k4  = (lane & 4)  == 0; XORST(fx4,  k4);
      const bool k2  = (lane & 2)  == 0; XORST(fx2,  k2);
      const bool k1  = (lane & 1)  == 0; XORST(fx1,  k1); TAIL4(); }

#undef TAIL4
#undef MIRROR
#undef XORST
}

// ---------- kernel 0: tile-transpose q,k -> qt,kt[bh][d][e] as f2ord u32 ---
__global__ __launch_bounds__(256) void swd3_transpose(
    const float* __restrict__ q, const float* __restrict__ k,
    uint32_t* __restrict__ qt, uint32_t* __restrict__ kt)
{
    __shared__ uint32_t tq[64][65];                 // +1 pad: col reads
    __shared__ uint32_t tk[64][65];                 //   conflict-free

    const int b  = blockIdx.x;                      // 0..1023
    const int bh = (b & 7) * 8 + ((b >> 3) & 7);    // XCD b%8 <-> bh>>3
    const int e0 = (b >> 6) * 64;                   // e-tile 0..15
    const int t  = threadIdx.x;

    const size_t base = (size_t)bh * (LL * DD);
    #pragma unroll
    for (int i = 0; i < 4; ++i) {
        const int idx = i * 256 + t;                // 0..1023
        const int r   = idx >> 4;                   // row in tile 0..63
        const int c   = (idx & 15) * 4;             // col 0,4,..,60
        const vf4 vq = *(const vf4*)(q + base + (size_t)(e0 + r) * DD + c);
        const vf4 vk = *(const vf4*)(k + base + (size_t)(e0 + r) * DD + c);
        tq[r][c + 0] = f2ord(vq.x); tq[r][c + 1] = f2ord(vq.y);
        tq[r][c + 2] = f2ord(vq.z); tq[r][c + 3] = f2ord(vq.w);
        tk[r][c + 0] = f2ord(vk.x); tk[r][c + 1] = f2ord(vk.y);
        tk[r][c + 2] = f2ord(vk.z); tk[r][c + 3] = f2ord(vk.w);
    }
    __syncthreads();
    #pragma unroll
    for (int i = 0; i < 4; ++i) {
        const int idx = i * 256 + t;
        const int d   = idx >> 4;                   // out row (dim) 0..63
        const int c   = (idx & 15) * 4;             // e-offset in tile
        vu4 v;
        v.x = tq[c + 0][d]; v.y = tq[c + 1][d];
        v.z = tq[c + 2][d]; v.w = tq[c + 3][d];
        *(vu4*)(qt + base + (size_t)d * LL + e0 + c) = v;
        v.x = tk[c + 0][d]; v.y = tk[c + 1][d];
        v.z = tk[c + 2][d]; v.w = tk[c + 3][d];
        *(vu4*)(kt + base + (size_t)d * LL + e0 + c) = v;
    }
}

// ---------- phase 1: coalesced loads + mirror/DPP bitonic argsort ----------
__global__ __launch_bounds__(256, 3) void swd3_phase1(
    const uint32_t* __restrict__ qt, const uint32_t* __restrict__ kt,
    uint32_t* __restrict__ pairs)
{
    __shared__ alignas(16) uint32_t pr[4][LL];      // 4 KiB per wave, private

    const int raw  = blockIdx.x;                    // 0..1023
    const int slot = raw >> 3;                      // 0..127
    const int bh   = (raw & 7) * 8 + (slot >> 4);   // XCD raw%8 <-> bh>>3
    const int dg   = slot & 15;
    const int t    = threadIdx.x;
    const int w    = t >> 6;                        // wave 0..3
    const int lane = t & 63;
    const int d    = dg * 4 + w;
    const int addr63 = (lane ^ 63) << 2;            // bpermute byte addr

    const uint32_t* colq = qt + (size_t)bh * (DD * LL) + (size_t)d * LL;
    const uint32_t* colk = kt + (size_t)bh * (DD * LL) + (size_t)d * LL;

    uint64_t xq[16], xk[16];
    #pragma unroll
    for (int r = 0; r < 4; ++r) {
        const vu4 vq = *(const vu4*)(colq + 256 * r + 4 * lane);
        const vu4 vk = *(const vu4*)(colk + 256 * r + 4 * lane);
        const uint32_t eb = 256u * r + 4u * lane;
        xq[4 * r + 0] = ((uint64_t)vq.x << 32) | (eb + 0);
        xq[4 * r + 1] = ((uint64_t)vq.y << 32) | (eb + 1);
        xq[4 * r + 2] = ((uint64_t)vq.z << 32) | (eb + 2);
        xq[4 * r + 3] = ((uint64_t)vq.w << 32) | (eb + 3);
        xk[4 * r + 0] = ((uint64_t)vk.x << 32) | (eb + 0);
        xk[4 * r + 1] = ((uint64_t)vk.y << 32) | (eb + 1);
        xk[4 * r + 2] = ((uint64_t)vk.z << 32) | (eb + 2);
        xk[4 * r + 3] = ((uint64_t)vk.w << 32) | (eb + 3);
    }
    wave_sort1024(xq, lane, addr63);
    wave_sort1024(xk, lane, addr63);

    // rank r pairs q-rank-r with k-rank-r; scatter packed
    // {val fp32 top22, low10 = k-index} by q-index into wave-private LDS.
    uint32_t* prw = pr[w];
    #pragma unroll
    for (int s = 0; s < 16; ++s) {
        const uint32_t iq = (uint32_t)xq[s] & 1023u;
        const uint32_t ik = (uint32_t)xk[s] & 1023u;
        const float df = ord2f((uint32_t)(xq[s] >> 32))
                       - ord2f((uint32_t)(xk[s] >> 32));
        const float val = __expf(-df * df) * (1.0f / 64.0f);
        prw[iq] = (__float_as_uint(val) & 0xFFFFFC00u) | ik;   // rel err<2^-12
    }
    __asm__ volatile("s_waitcnt lgkmcnt(0)" ::: "memory");  // wave-local drain
    vu4* pp4 = (vu4*)(pairs + ((size_t)bh * DD + d) * LL);
    const vu4* src = (const vu4*)prw;
    #pragma unroll
    for (int r = 0; r < 4; ++r)
        pp4[r * 64 + lane] = src[r * 64 + lane];
}

// ---------- phase 2: R5 block structure at 4 rows/block (16 KiB LDS) -------
__global__ __launch_bounds__(256) void swd3_phase2(
    const uint32_t* __restrict__ pairs, const void* __restrict__ maskp,
    float* __restrict__ out)
{
    __shared__ alignas(16) float acc[4 * LL];       // 16 KiB
    __shared__ uint32_t sdet[4];

    const int b  = blockIdx.x;                      // 0..16383
    const int bh = (b & 7) * 8 + ((b >> 3) & 7);    // XCD b%8 <-> bh>>3
    const int st = b >> 6;                          // stripe 0..255
    const int i0 = st * 4;
    const int t  = threadIdx.x;

    // inline mask-width detect on the globally-shared first 1 KiB of mask
    {
        const uint32_t w = ((const uint32_t*)maskp)[t];
        const uint64_t bal = __ballot(w > 1u);
        if ((t & 63) == 0) sdet[t >> 6] = (bal != 0ull) ? 1u : 0u;
    }

    vf4* acc4 = (vf4*)acc;
    #pragma unroll
    for (int v = 0; v < 4; ++v) {
        vf4 z; z.x = 0.f; z.y = 0.f; z.z = 0.f; z.w = 0.f;
        acc4[v * 256 + t] = z;
    }
    __syncthreads();

    const bool mask_byte =
        ((sdet[0] | sdet[1] | sdet[2] | sdet[3]) != 0u);
    const size_t cellbase = ((size_t)bh << 20) + ((size_t)i0 << 10);

    // prefetch mask into registers (NT); loads fly during the LDS scatter
    uint32_t mb[4];
    vi4      mi[4];
    if (mask_byte) {
        const uint32_t* mp = (const uint32_t*)maskp + (cellbase >> 2);
        #pragma unroll
        for (int v = 0; v < 4; ++v)
            mb[v] = __builtin_nontemporal_load(mp + v * 256 + t);
    } else {
        const vi4* mp = (const vi4*)((const int32_t*)maskp + cellbase);
        #pragma unroll
        for (int v = 0; v < 4; ++v)
            mi[v] = __builtin_nontemporal_load(mp + v * 256 + t);
    }

    // 256 records: thread t -> dd = t>>2, row r = t&3 (16B quad per dd)
    {
        const uint32_t* pb = pairs + (size_t)bh * (DD * LL);
        const int dd = t >> 2;
        const int r  = t & 3;
        const uint32_t pv = pb[(size_t)dd * LL + i0 + r];
        atomicAdd(&acc[r * LL + (int)(pv & 1023u)],
                  __uint_as_float(pv & 0xFFFFFC00u));
    }
    __syncthreads();

    vf4* ob = (vf4*)(out + cellbase);
    #pragma unroll
    for (int v = 0; v < 4; ++v) {
        const int p = v * 256 + t;                  // vf4 group in [0,1024)
        const vf4 a = acc4[p];
        int mx, my, mz, mw2;
        if (mask_byte) {
            const uint32_t m = mb[v];
            mx = (int)(m & 0xFFu); my = (int)((m >> 8) & 0xFFu);
            mz = (int)((m >> 16) & 0xFFu); mw2 = (int)(m >> 24);
        } else {
            mx = mi[v].x; my = mi[v].y; mz = mi[v].z; mw2 = mi[v].w;
        }
        vf4 r;
        r.x = mx  ? 0.f : a.x;
        r.y = my  ? 0.f : a.y;
        r.z = mz  ? 0.f : a.z;
        r.w = mw2 ? 0.f : a.w;
        __builtin_nontemporal_store(r, ob + p);
    }
}

extern "C" void kernel_launch(void* const* d_in, const int* in_sizes, int n_in,
                              void* d_out, int out_size, void* d_ws, size_t ws_size,
                              hipStream_t stream) {
    const float* q = (const float*)d_in[0];
    const float* k = (const float*)d_in[1];
    const void* mask = d_in[2];
    uint32_t* pairs = (uint32_t*)d_ws;
    uint32_t* qt = pairs + MAT_WORDS;
    uint32_t* kt = qt + MAT_WORDS;

    const bool ws_ok = (ws_size >= WS_BYTES);
    hipError_t e0 = hipSuccess, e1 = hipSuccess, e2 = hipSuccess;
    (void)hipGetLastError();

    if (ws_ok) {
        swd3_transpose<<<NBH * 16, 256, 0, stream>>>(q, k, qt, kt);
        e0 = hipGetLastError();
        swd3_phase1<<<NBH * DD / 4, 256, 0, stream>>>(qt, kt, pairs);
        e1 = hipGetLastError();
        swd3_phase2<<<NBH * 256, 256, 0, stream>>>(pairs, mask, (float*)d_out);
        e2 = hipGetLastError();
    }

    if (!ws_ok || e0 != hipSuccess || e1 != hipSuccess || e2 != hipSuccess) {
        // Diagnostic stamp (fp32 codes): absmax reveals which enqueue failed.
        static float h_stamp[8];
        h_stamp[0] = !ws_ok ? (9000.0f + (float)(ws_size >> 20))
                            : (1000.0f + (float)(int)e0);
        h_stamp[1] = 2000.0f + (float)(int)e1;
        h_stamp[2] = 3000.0f + (float)(int)e2;
        h_stamp[3] = h_stamp[0];
        hipMemcpyAsync(d_out, h_stamp, sizeof(h_stamp),
                       hipMemcpyHostToDevice, stream);
    }
}

// Round 9
// 509.036 us; speedup vs baseline: 1.1980x; 1.0045x over previous
//
#include <hip/hip_runtime.h>
#include <stdint.h>
#include <string.h>

// B=4,H=16,L=1024,D=64. q,k: fp32 [B,H,L,D]; mask: int32 bool on this
// harness (byte handled too, runtime detect); out: fp32 [B,H,L,L].
// out[bh,i,j] = mask ? 0 : sum_d exp(-(qs-ks)^2)/64, rank-paired via stable
// per-(bh,d) argsort of q and k columns.
//
// FINAL (R9). Session ledger:
//   baseline 551.6 -> 507.0 (R5, best) via:
//   - transpose kernel (f2ord fused) -> coalesced p1 loads   [R4]
//   - mirror-first all-ascending bitonic w/ DPP exchanges:
//     21 DS-pipe steps/sort -> 3 (p1 79.5 -> ~21us)          [R5]
//   - XCD-aligned bh mapping across all kernels              [R4]
//   p2 = 101us @ ~83% of mixed R/W achievable BW (528MB: mask 256 int32 +
//   pairs 16 fetch, out 256 write). Probed: block-8 (101) < block-4 (flat,
//   R8) < wave-autonomous (121, R7) -> 8-row block is the right structure.
//   Fixed harness overhead (2x 1GiB ws-poison fills + out fill + gaps)
//   ~= 375us. Floor ~= 482; this kernel ~= 507 (within ~5%).
// THIS ROUND: revert p2 to the R5-proven 8-row block (R8's 4-row was the
// only delta vs R5 and was neutral/worse). Everything else R5-identical.

#define LL 1024
#define DD 64
#define NBH 64
#define MAT_WORDS ((size_t)NBH * DD * LL)          // 4 Mi words = 16 MiB
#define WS_BYTES (3 * MAT_WORDS * 4)               // pairs + qt + kt = 48 MiB

typedef float    vf4   __attribute__((ext_vector_type(4)));
typedef uint32_t vu4   __attribute__((ext_vector_type(4)));
typedef int32_t  vi4   __attribute__((ext_vector_type(4)));

__device__ __forceinline__ uint32_t f2ord(float x) {
    uint32_t u = __float_as_uint(x);
    return (u & 0x80000000u) ? ~u : (u | 0x80000000u);
}
__device__ __forceinline__ float ord2f(uint32_t o) {
    uint32_t u = (o & 0x80000000u) ? (o & 0x7fffffffu) : ~o;
    return __uint_as_float(u);
}

// ---- cross-lane fetch primitives (u64 as 2 dwords) ----
template <int CTRL>
__device__ __forceinline__ uint64_t dpp64(uint64_t v) {
    const uint32_t lo = (uint32_t)__builtin_amdgcn_update_dpp(
        0, (int)(uint32_t)v, CTRL, 0xF, 0xF, true);
    const uint32_t hi = (uint32_t)__builtin_amdgcn_update_dpp(
        0, (int)(uint32_t)(v >> 32), CTRL, 0xF, 0xF, true);
    return ((uint64_t)hi << 32) | lo;
}
template <int PATT>
__device__ __forceinline__ uint64_t swz64(uint64_t v) {
    const uint32_t lo = (uint32_t)__builtin_amdgcn_ds_swizzle(
        (int)(uint32_t)v, PATT);
    const uint32_t hi = (uint32_t)__builtin_amdgcn_ds_swizzle(
        (int)(uint32_t)(v >> 32), PATT);
    return ((uint64_t)hi << 32) | lo;
}
__device__ __forceinline__ uint64_t bper64(uint64_t v, int addr) {
    const uint32_t lo = (uint32_t)__builtin_amdgcn_ds_bpermute(
        addr, (int)(uint32_t)v);
    const uint32_t hi = (uint32_t)__builtin_amdgcn_ds_bpermute(
        addr, (int)(uint32_t)(v >> 32));
    return ((uint64_t)hi << 32) | lo;
}
// lane-xor fetchers: x1,x2 direct quad_perm; x4=^7∘^3, x8=^15∘^7 composed;
// x3,x7,x15 are lane-mirrors; x16,x31 ds_swizzle BitMode.
__device__ __forceinline__ uint64_t fx1 (uint64_t v){ return dpp64<0xB1>(v); }
__device__ __forceinline__ uint64_t fx2 (uint64_t v){ return dpp64<0x4E>(v); }
__device__ __forceinline__ uint64_t fx3 (uint64_t v){ return dpp64<0x1B>(v); }
__device__ __forceinline__ uint64_t fx4 (uint64_t v){ return dpp64<0x1B>(dpp64<0x141>(v)); }
__device__ __forceinline__ uint64_t fx7 (uint64_t v){ return dpp64<0x141>(v); }
__device__ __forceinline__ uint64_t fx8 (uint64_t v){ return dpp64<0x141>(dpp64<0x140>(v)); }
__device__ __forceinline__ uint64_t fx15(uint64_t v){ return dpp64<0x140>(v); }
__device__ __forceinline__ uint64_t fx16(uint64_t v){ return swz64<0x401F>(v); }
__device__ __forceinline__ uint64_t fx31(uint64_t v){ return swz64<0x7C1F>(v); }

// full ascending sort of 1024 u64 keys, element p = 16*lane + s.
// Mirror-first bitonic: every merge S starts with mirror CE (p <-> S-1-p),
// then xor steps S/4..1, ALL directions ascending (no up/down logic).
__device__ __forceinline__ void wave_sort1024(uint64_t x[16], const int lane,
                                              const int addr63)
{
    auto cexA = [](uint64_t& a, uint64_t& b) {
        const uint64_t lo = a < b ? a : b;
        const uint64_t hi = a < b ? b : a;
        a = lo; b = hi;
    };
    auto sel = [](uint64_t xv, uint64_t y, bool km) {
        return ((xv < y) == km) ? xv : y;      // km: keep min, else keep max
    };

#define TAIL4() do { _Pragma("unroll") \
    for (int j = 8; j >= 1; j >>= 1) { _Pragma("unroll") \
        for (int s = 0; s < 16; ++s) \
            if (!(s & j)) cexA(x[s], x[s | j]); } } while (0)

#define MIRROR(F, KM) do { _Pragma("unroll") \
    for (int i = 0; i < 8; ++i) { \
        const uint64_t ya = F(x[15 - i]); \
        const uint64_t yb = F(x[i]); \
        x[i]      = sel(x[i],      ya, (KM)); \
        x[15 - i] = sel(x[15 - i], yb, (KM)); } } while (0)

#define XORST(F, KM) do { _Pragma("unroll") \
    for (int s = 0; s < 16; ++s) { \
        const uint64_t y = F(x[s]); \
        x[s] = sel(x[s], y, (KM)); } } while (0)

    // ---- in-register prelude: S = 2,4,8,16 (per-lane 16-elem sort) ----
    #pragma unroll
    for (int s = 0; s < 16; s += 2) cexA(x[s], x[s + 1]);          // S=2
    #pragma unroll
    for (int b = 0; b < 16; b += 4) {                              // S=4 M
        cexA(x[b], x[b + 3]); cexA(x[b + 1], x[b + 2]);
    }
    #pragma unroll
    for (int s = 0; s < 16; s += 2) cexA(x[s], x[s + 1]);          // S=4 j1
    #pragma unroll
    for (int b = 0; b < 16; b += 8) {                              // S=8 M
        cexA(x[b], x[b + 7]); cexA(x[b + 1], x[b + 6]);
        cexA(x[b + 2], x[b + 5]); cexA(x[b + 3], x[b + 4]);
    }
    #pragma unroll
    for (int j = 2; j >= 1; j >>= 1) {                             // S=8 tail
        #pragma unroll
        for (int s = 0; s < 16; ++s)
            if (!(s & j)) cexA(x[s], x[s | j]);
    }
    #pragma unroll
    for (int i = 0; i < 8; ++i) cexA(x[i], x[15 - i]);             // S=16 M
    #pragma unroll
    for (int j = 4; j >= 1; j >>= 1) {                             // S=16 tail
        #pragma unroll
        for (int s = 0; s < 16; ++s)
            if (!(s & j)) cexA(x[s], x[s | j]);
    }

    // ---- cross-lane merges ----
    { const bool km = (lane & 1) == 0;                 // S=32
      MIRROR(fx1, km); TAIL4(); }
    { const bool kmM = (lane & 2) == 0;                // S=64
      MIRROR(fx3, kmM);
      const bool k1 = (lane & 1) == 0; XORST(fx1, k1); TAIL4(); }
    { const bool kmM = (lane & 4) == 0;                // S=128
      MIRROR(fx7, kmM);
      const bool k2 = (lane & 2) == 0; XORST(fx2, k2);
      const bool k1 = (lane & 1) == 0; XORST(fx1, k1); TAIL4(); }
    { const bool kmM = (lane & 8) == 0;                // S=256
      MIRROR(fx15, kmM);
      const bool k4 = (lane & 4) == 0; XORST(fx4, k4);
      const bool k2 = (lane & 2) == 0; XORST(fx2, k2);
      const bool k1 = (lane & 1) == 0; XORST(fx1, k1); TAIL4(); }
    { const bool kmM = (lane & 16) == 0;               // S=512
      MIRROR(fx31, kmM);
      const bool k8 = (lane & 8) == 0; XORST(fx8, k8);
      const bool k4 = (lane & 4) == 0; XORST(fx4, k4);
      const bool k2 = (lane & 2) == 0; XORST(fx2, k2);
      const bool k1 = (lane & 1) == 0; XORST(fx1, k1); TAIL4(); }
    { const bool kmM = (lane & 32) == 0;               // S=1024
      #pragma unroll
      for (int i = 0; i < 8; ++i) {                    // mirror ^63: bpermute
          const uint64_t ya = bper64(x[15 - i], addr63);
          const uint64_t yb = bper64(x[i], addr63);
          x[i]      = sel(x[i],      ya, kmM);
          x[15 - i] = sel(x[15 - i], yb, kmM);
      }
      const bool k16 = (lane & 16) == 0; XORST(fx16, k16);
      const bool k8  = (lane & 8)  == 0; XORST(fx8,  k8);
      const bool k4  = (lane & 4)  == 0; XORST(fx4,  k4);
      const bool k2  = (lane & 2)  == 0; XORST(fx2,  k2);
      const bool k1  = (lane & 1)  == 0; XORST(fx1,  k1); TAIL4(); }

#undef TAIL4
#undef MIRROR
#undef XORST
}

// ---------- kernel 0: tile-transpose q,k -> qt,kt[bh][d][e] as f2ord u32 ---
__global__ __launch_bounds__(256) void swd3_transpose(
    const float* __restrict__ q, const float* __restrict__ k,
    uint32_t* __restrict__ qt, uint32_t* __restrict__ kt)
{
    __shared__ uint32_t tq[64][65];                 // +1 pad: col reads
    __shared__ uint32_t tk[64][65];                 //   conflict-free

    const int b  = blockIdx.x;                      // 0..1023
    const int bh = (b & 7) * 8 + ((b >> 3) & 7);    // XCD b%8 <-> bh>>3
    const int e0 = (b >> 6) * 64;                   // e-tile 0..15
    const int t  = threadIdx.x;

    const size_t base = (size_t)bh * (LL * DD);
    #pragma unroll
    for (int i = 0; i < 4; ++i) {
        const int idx = i * 256 + t;                // 0..1023
        const int r   = idx >> 4;                   // row in tile 0..63
        const int c   = (idx & 15) * 4;             // col 0,4,..,60
        const vf4 vq = *(const vf4*)(q + base + (size_t)(e0 + r) * DD + c);
        const vf4 vk = *(const vf4*)(k + base + (size_t)(e0 + r) * DD + c);
        tq[r][c + 0] = f2ord(vq.x); tq[r][c + 1] = f2ord(vq.y);
        tq[r][c + 2] = f2ord(vq.z); tq[r][c + 3] = f2ord(vq.w);
        tk[r][c + 0] = f2ord(vk.x); tk[r][c + 1] = f2ord(vk.y);
        tk[r][c + 2] = f2ord(vk.z); tk[r][c + 3] = f2ord(vk.w);
    }
    __syncthreads();
    #pragma unroll
    for (int i = 0; i < 4; ++i) {
        const int idx = i * 256 + t;
        const int d   = idx >> 4;                   // out row (dim) 0..63
        const int c   = (idx & 15) * 4;             // e-offset in tile
        vu4 v;
        v.x = tq[c + 0][d]; v.y = tq[c + 1][d];
        v.z = tq[c + 2][d]; v.w = tq[c + 3][d];
        *(vu4*)(qt + base + (size_t)d * LL + e0 + c) = v;
        v.x = tk[c + 0][d]; v.y = tk[c + 1][d];
        v.z = tk[c + 2][d]; v.w = tk[c + 3][d];
        *(vu4*)(kt + base + (size_t)d * LL + e0 + c) = v;
    }
}

// ---------- phase 1: coalesced loads + mirror/DPP bitonic argsort ----------
__global__ __launch_bounds__(256, 3) void swd3_phase1(
    const uint32_t* __restrict__ qt, const uint32_t* __restrict__ kt,
    uint32_t* __restrict__ pairs)
{
    __shared__ alignas(16) uint32_t pr[4][LL];      // 4 KiB per wave, private

    const int raw  = blockIdx.x;                    // 0..1023
    const int slot = raw >> 3;                      // 0..127
    const int bh   = (raw & 7) * 8 + (slot >> 4);   // XCD raw%8 <-> bh>>3
    const int dg   = slot & 15;
    const int t    = threadIdx.x;
    const int w    = t >> 6;                        // wave 0..3
    const int lane = t & 63;
    const int d    = dg * 4 + w;
    const int addr63 = (lane ^ 63) << 2;            // bpermute byte addr

    const uint32_t* colq = qt + (size_t)bh * (DD * LL) + (size_t)d * LL;
    const uint32_t* colk = kt + (size_t)bh * (DD * LL) + (size_t)d * LL;

    uint64_t xq[16], xk[16];
    #pragma unroll
    for (int r = 0; r < 4; ++r) {
        const vu4 vq = *(const vu4*)(colq + 256 * r + 4 * lane);
        const vu4 vk = *(const vu4*)(colk + 256 * r + 4 * lane);
        const uint32_t eb = 256u * r + 4u * lane;
        xq[4 * r + 0] = ((uint64_t)vq.x << 32) | (eb + 0);
        xq[4 * r + 1] = ((uint64_t)vq.y << 32) | (eb + 1);
        xq[4 * r + 2] = ((uint64_t)vq.z << 32) | (eb + 2);
        xq[4 * r + 3] = ((uint64_t)vq.w << 32) | (eb + 3);
        xk[4 * r + 0] = ((uint64_t)vk.x << 32) | (eb + 0);
        xk[4 * r + 1] = ((uint64_t)vk.y << 32) | (eb + 1);
        xk[4 * r + 2] = ((uint64_t)vk.z << 32) | (eb + 2);
        xk[4 * r + 3] = ((uint64_t)vk.w << 32) | (eb + 3);
    }
    wave_sort1024(xq, lane, addr63);
    wave_sort1024(xk, lane, addr63);

    // rank r pairs q-rank-r with k-rank-r; scatter packed
    // {val fp32 top22, low10 = k-index} by q-index into wave-private LDS.
    uint32_t* prw = pr[w];
    #pragma unroll
    for (int s = 0; s < 16; ++s) {
        const uint32_t iq = (uint32_t)xq[s] & 1023u;
        const uint32_t ik = (uint32_t)xk[s] & 1023u;
        const float df = ord2f((uint32_t)(xq[s] >> 32))
                       - ord2f((uint32_t)(xk[s] >> 32));
        const float val = __expf(-df * df) * (1.0f / 64.0f);
        prw[iq] = (__float_as_uint(val) & 0xFFFFFC00u) | ik;   // rel err<2^-12
    }
    __asm__ volatile("s_waitcnt lgkmcnt(0)" ::: "memory");  // wave-local drain
    vu4* pp4 = (vu4*)(pairs + ((size_t)bh * DD + d) * LL);
    const vu4* src = (const vu4*)prw;
    #pragma unroll
    for (int r = 0; r < 4; ++r)
        pp4[r * 64 + lane] = src[r * 64 + lane];
}

// ---------- phase 2: 8-row block assembly (R5-proven best structure) -------
__global__ __launch_bounds__(256) void swd3_phase2(
    const uint32_t* __restrict__ pairs, const void* __restrict__ maskp,
    float* __restrict__ out)
{
    __shared__ alignas(16) float acc[8 * LL];       // 32 KiB
    __shared__ uint32_t sdet[4];

    const int b  = blockIdx.x;                      // 0..8191
    const int bh = (b & 7) * 8 + ((b >> 3) & 7);    // XCD b%8 <-> bh>>3
    const int st = b >> 6;                          // stripe 0..127
    const int i0 = st * 8;
    const int t  = threadIdx.x;

    // inline mask-width detect on the globally-shared first 1 KiB of mask
    {
        const uint32_t w = ((const uint32_t*)maskp)[t];
        const uint64_t bal = __ballot(w > 1u);
        if ((t & 63) == 0) sdet[t >> 6] = (bal != 0ull) ? 1u : 0u;
    }

    vf4* acc4 = (vf4*)acc;
    #pragma unroll
    for (int v = 0; v < 8; ++v) {
        vf4 z; z.x = 0.f; z.y = 0.f; z.z = 0.f; z.w = 0.f;
        acc4[v * 256 + t] = z;
    }
    __syncthreads();

    const bool mask_byte =
        ((sdet[0] | sdet[1] | sdet[2] | sdet[3]) != 0u);
    const size_t cellbase = ((size_t)bh << 20) + ((size_t)i0 << 10);

    // prefetch mask into registers (NT); loads fly during the LDS scatter
    uint32_t mb[8];
    vi4      mi[8];
    if (mask_byte) {
        const uint32_t* mp = (const uint32_t*)maskp + (cellbase >> 2);
        #pragma unroll
        for (int v = 0; v < 8; ++v)
            mb[v] = __builtin_nontemporal_load(mp + v * 256 + t);
    } else {
        const vi4* mp = (const vi4*)((const int32_t*)maskp + cellbase);
        #pragma unroll
        for (int v = 0; v < 8; ++v)
            mi[v] = __builtin_nontemporal_load(mp + v * 256 + t);
    }

    // 512 records as 256 uint2: thread t -> dd=t>>2, rows 2*(t&3), 2*(t&3)+1
    {
        const uint32_t* pb = pairs + (size_t)bh * (DD * LL);
        const int dd = t >> 2;
        const uint2 pv = ((const uint2*)(pb + dd * LL + i0))[t & 3];
        const int ii0 = 2 * (t & 3), ii1 = ii0 + 1;
        atomicAdd(&acc[ii0 * LL + (int)(pv.x & 1023u)],
                  __uint_as_float(pv.x & 0xFFFFFC00u));
        atomicAdd(&acc[ii1 * LL + (int)(pv.y & 1023u)],
                  __uint_as_float(pv.y & 0xFFFFFC00u));
    }
    __syncthreads();

    vf4* ob = (vf4*)(out + cellbase);
    #pragma unroll
    for (int v = 0; v < 8; ++v) {
        const int p = v * 256 + t;                  // vf4 group in [0,2048)
        const vf4 a = acc4[p];
        int mx, my, mz, mw2;
        if (mask_byte) {
            const uint32_t m = mb[v];
            mx = (int)(m & 0xFFu); my = (int)((m >> 8) & 0xFFu);
            mz = (int)((m >> 16) & 0xFFu); mw2 = (int)(m >> 24);
        } else {
            mx = mi[v].x; my = mi[v].y; mz = mi[v].z; mw2 = mi[v].w;
        }
        vf4 r;
        r.x = mx  ? 0.f : a.x;
        r.y = my  ? 0.f : a.y;
        r.z = mz  ? 0.f : a.z;
        r.w = mw2 ? 0.f : a.w;
        __builtin_nontemporal_store(r, ob + p);
    }
}

extern "C" void kernel_launch(void* const* d_in, const int* in_sizes, int n_in,
                              void* d_out, int out_size, void* d_ws, size_t ws_size,
                              hipStream_t stream) {
    const float* q = (const float*)d_in[0];
    const float* k = (const float*)d_in[1];
    const void* mask = d_in[2];
    uint32_t* pairs = (uint32_t*)d_ws;
    uint32_t* qt = pairs + MAT_WORDS;
    uint32_t* kt = qt + MAT_WORDS;

    const bool ws_ok = (ws_size >= WS_BYTES);
    hipError_t e0 = hipSuccess, e1 = hipSuccess, e2 = hipSuccess;
    (void)hipGetLastError();

    if (ws_ok) {
        swd3_transpose<<<NBH * 16, 256, 0, stream>>>(q, k, qt, kt);
        e0 = hipGetLastError();
        swd3_phase1<<<NBH * DD / 4, 256, 0, stream>>>(qt, kt, pairs);
        e1 = hipGetLastError();
        swd3_phase2<<<NBH * 128, 256, 0, stream>>>(pairs, mask, (float*)d_out);
        e2 = hipGetLastError();
    }

    if (!ws_ok || e0 != hipSuccess || e1 != hipSuccess || e2 != hipSuccess) {
        // Diagnostic stamp (fp32 codes): absmax reveals which enqueue failed.
        static float h_stamp[8];
        h_stamp[0] = !ws_ok ? (9000.0f + (float)(ws_size >> 20))
                            : (1000.0f + (float)(int)e0);
        h_stamp[1] = 2000.0f + (float)(int)e1;
        h_stamp[2] = 3000.0f + (float)(int)e2;
        h_stamp[3] = h_stamp[0];
        hipMemcpyAsync(d_out, h_stamp, sizeof(h_stamp),
                       hipMemcpyHostToDevice, stream);
    }
}